// Round 2
// baseline (139.755 us; speedup 1.0000x reference)
//
#include <hip/hip_runtime.h>

#define SN 524288   // number of columns in the (64, SN) view of x

typedef float f32x4 __attribute__((ext_vector_type(4)));

// ---------------- Kernel A: build Ct[c*64 + i] = C[i][c], C = [B | M21] (64 x 128) ---
__global__ __launch_bounds__(256) void k_buildC(const float* __restrict__ L,
                                                const float* __restrict__ R,
                                                float* __restrict__ Ct) {
  __shared__ float4 Ls[4096];  // L (128x128) XOR-swizzled in float4 units
  const float4* L4 = (const float4*)L;
  #pragma unroll
  for (int it = 0; it < 16; ++it) {
    int idx = threadIdx.x + it * 256;
    int row = idx >> 5, t4 = idx & 31;
    Ls[(row << 5) + (t4 ^ (row & 7))] = L4[idx];
  }
  __syncthreads();
  int g = blockIdx.x * 256 + threadIdx.x;  // 0..8191
  int c = g >> 6;                          // column of C, uniform per wave
  int i = g & 63;                          // row of C = lane
  if (c < 64) {
    float d1 = 0.f, d2 = 0.f;
    #pragma unroll
    for (int t4 = 0; t4 < 32; ++t4) {
      float4 a1 = Ls[(i << 5) + (t4 ^ (i & 7))];
      float4 b1 = Ls[(c << 5) + (t4 ^ (c & 7))];
      float4 a2 = Ls[((64 + i) << 5) + (t4 ^ (i & 7))];
      float4 b2 = Ls[((64 + c) << 5) + (t4 ^ (c & 7))];
      d1 += a1.x * b1.x + a1.y * b1.y + a1.z * b1.z + a1.w * b1.w;
      d2 += a2.x * b2.x + a2.y * b2.y + a2.z * b2.z + a2.w * b2.w;
    }
    float val = 2.0f * (d1 + d2 + R[i * 64 + c] - R[c * 64 + i]);
    if (i == c) val += 4e-8f;
    Ct[c * 64 + i] = val;
  } else {
    int jj = c - 64;
    float d = 0.f;
    #pragma unroll
    for (int t4 = 0; t4 < 32; ++t4) {
      float4 a = Ls[(i << 5) + (t4 ^ (i & 7))];
      float4 b = Ls[((64 + jj) << 5) + (t4 ^ (jj & 7))];
      d += a.x * b.x + a.y * b.y + a.z * b.z + a.w * b.w;
    }
    Ct[c * 64 + i] = d;
  }
}

// ---------------- Kernel B: Gauss-Jordan solve B A = M21, write At[k*64+i] = A[i][k] ---
__global__ __launch_bounds__(256) void k_solve(const float* __restrict__ Ct,
                                               float* __restrict__ At) {
  __shared__ float colbuf[2][64];
  __shared__ __align__(16) float rowbuf[2][128];
  const int r = threadIdx.x & 63;
  const int cgrp = threadIdx.x >> 6;
  float creg[32];
  #pragma unroll
  for (int cc = 0; cc < 32; ++cc)
    creg[cc] = Ct[(cgrp * 32 + cc) * 64 + r];
  #pragma unroll
  for (int p = 0; p < 64; ++p) {
    const int pb = p & 1, pc = p >> 5, pi = p & 31;
    if (cgrp == pc) colbuf[pb][r] = creg[pi];
    if (r == p) {
      #pragma unroll
      for (int cc = 0; cc < 32; ++cc) rowbuf[pb][cgrp * 32 + cc] = creg[cc];
    }
    __syncthreads();
    const float f = colbuf[pb][r];
    const float inv = 1.0f / colbuf[pb][p];
    if (r == p) {
      #pragma unroll
      for (int cc = 0; cc < 32; ++cc) creg[cc] *= inv;
    } else {
      const float gg = f * inv;
      #pragma unroll
      for (int c4 = 0; c4 < 8; ++c4) {
        const float4 pv = *(const float4*)&rowbuf[pb][cgrp * 32 + c4 * 4];
        creg[c4 * 4 + 0] -= gg * pv.x;
        creg[c4 * 4 + 1] -= gg * pv.y;
        creg[c4 * 4 + 2] -= gg * pv.z;
        creg[c4 * 4 + 3] -= gg * pv.w;
      }
    }
  }
  if (cgrp >= 2) {
    #pragma unroll
    for (int cc = 0; cc < 32; ++cc) {
      int k = (cgrp - 2) * 32 + cc;
      At[k * 64 + r] = creg[cc];
    }
  }
}

// ---------------- Kernel C: out = A @ X, X = x viewed (64, SN) ------------------------
// Block = 4 waves sharing one 512-float j-window; wave w owns i-quarter [16w,16w+16).
// Per thread: acc[16][8]. Per k-step: 4 uniform ds_read_b128 (A), 2 coalesced
// dwordx4 x-loads (1-deep prefetched), 128 FMAs. NT stores keep x L3-resident.
__global__ __launch_bounds__(256, 3) void k_apply(const float* __restrict__ x,
                                                  const float* __restrict__ At,
                                                  float* __restrict__ out) {
  __shared__ f32x4 Al[1024];  // Al[k*16 + i4] = A[4*i4 .. 4*i4+3][k]
  const f32x4* At4 = (const f32x4*)At;
  #pragma unroll
  for (int it = 0; it < 4; ++it)
    Al[threadIdx.x + it * 256] = At4[threadIdx.x + it * 256];
  __syncthreads();

  const int lane = threadIdx.x & 63;
  const int w = threadIdx.x >> 6;          // i-quarter
  const int c0 = blockIdx.x * 128 + lane;  // float4-column, chunk 0
  const int c1 = c0 + 64;                  // chunk 1
  const f32x4* x4 = (const f32x4*)x;
  f32x4* out4 = (f32x4*)out;

  float acc[16][8];
  #pragma unroll
  for (int i = 0; i < 16; ++i)
    #pragma unroll
    for (int j = 0; j < 8; ++j) acc[i][j] = 0.f;

  f32x4 xa = x4[c0];
  f32x4 xb = x4[c1];
  #pragma unroll 2
  for (int k = 0; k < 64; ++k) {
    f32x4 na, nb;
    if (k < 63) {
      na = x4[(k + 1) * (SN / 4) + c0];
      nb = x4[(k + 1) * (SN / 4) + c1];
    }
    #pragma unroll
    for (int q = 0; q < 4; ++q) {
      const f32x4 a = Al[(k << 4) + (w << 2) + q];  // uniform -> LDS broadcast
      #pragma unroll
      for (int r = 0; r < 4; ++r) {
        const float av = a[r];
        const int il = q * 4 + r;
        acc[il][0] += av * xa[0];
        acc[il][1] += av * xa[1];
        acc[il][2] += av * xa[2];
        acc[il][3] += av * xa[3];
        acc[il][4] += av * xb[0];
        acc[il][5] += av * xb[1];
        acc[il][6] += av * xb[2];
        acc[il][7] += av * xb[3];
      }
    }
    xa = na;
    xb = nb;
  }

  #pragma unroll
  for (int il = 0; il < 16; ++il) {
    const int i = w * 16 + il;
    f32x4 v0 = {acc[il][0], acc[il][1], acc[il][2], acc[il][3]};
    f32x4 v1 = {acc[il][4], acc[il][5], acc[il][6], acc[il][7]};
    __builtin_nontemporal_store(v0, &out4[i * (SN / 4) + c0]);
    __builtin_nontemporal_store(v1, &out4[i * (SN / 4) + c1]);
  }
}

extern "C" void kernel_launch(void* const* d_in, const int* in_sizes, int n_in,
                              void* d_out, int out_size, void* d_ws, size_t ws_size,
                              hipStream_t stream) {
  const float* x = (const float*)d_in[0];  // 524288 x 64
  const float* L = (const float*)d_in[1];  // 128 x 128
  const float* R = (const float*)d_in[2];  // 64 x 64
  float* out = (float*)d_out;
  float* Ct = (float*)d_ws;        // 128*64 f32 = 32 KB
  float* At = Ct + 128 * 64;       // 64*64 f32 = 16 KB
  k_buildC<<<32, 256, 0, stream>>>(L, R, Ct);
  k_solve<<<1, 256, 0, stream>>>(Ct, At);
  k_apply<<<1024, 256, 0, stream>>>(x, At, out);
}

// Round 3
// 108.458 us; speedup vs baseline: 1.2886x; 1.2886x over previous
//
#include <hip/hip_runtime.h>

#define SN 524288   // number of columns in the (64, SN) view of x

typedef float f32x4 __attribute__((ext_vector_type(4)));

// ---------------- Kernel A: build Ct[c*64 + i] = C[i][c], C = [B | M21] (64 x 128) ---
__global__ __launch_bounds__(256) void k_buildC(const float* __restrict__ L,
                                                const float* __restrict__ R,
                                                float* __restrict__ Ct) {
  __shared__ float4 Ls[4096];  // L (128x128) XOR-swizzled in float4 units
  const float4* L4 = (const float4*)L;
  #pragma unroll
  for (int it = 0; it < 16; ++it) {
    int idx = threadIdx.x + it * 256;
    int row = idx >> 5, t4 = idx & 31;
    Ls[(row << 5) + (t4 ^ (row & 7))] = L4[idx];
  }
  __syncthreads();
  int g = blockIdx.x * 256 + threadIdx.x;  // 0..8191
  int c = g >> 6;                          // column of C, uniform per wave
  int i = g & 63;                          // row of C = lane
  if (c < 64) {
    float d1 = 0.f, d2 = 0.f;
    #pragma unroll
    for (int t4 = 0; t4 < 32; ++t4) {
      float4 a1 = Ls[(i << 5) + (t4 ^ (i & 7))];
      float4 b1 = Ls[(c << 5) + (t4 ^ (c & 7))];
      float4 a2 = Ls[((64 + i) << 5) + (t4 ^ (i & 7))];
      float4 b2 = Ls[((64 + c) << 5) + (t4 ^ (c & 7))];
      d1 += a1.x * b1.x + a1.y * b1.y + a1.z * b1.z + a1.w * b1.w;
      d2 += a2.x * b2.x + a2.y * b2.y + a2.z * b2.z + a2.w * b2.w;
    }
    float val = 2.0f * (d1 + d2 + R[i * 64 + c] - R[c * 64 + i]);
    if (i == c) val += 4e-8f;
    Ct[c * 64 + i] = val;
  } else {
    int jj = c - 64;
    float d = 0.f;
    #pragma unroll
    for (int t4 = 0; t4 < 32; ++t4) {
      float4 a = Ls[(i << 5) + (t4 ^ (i & 7))];
      float4 b = Ls[((64 + jj) << 5) + (t4 ^ (jj & 7))];
      d += a.x * b.x + a.y * b.y + a.z * b.z + a.w * b.w;
    }
    Ct[c * 64 + i] = d;
  }
}

// ---------------- Kernel B: Gauss-Jordan solve B A = M21, write At[k*64+i] = A[i][k] ---
__global__ __launch_bounds__(256) void k_solve(const float* __restrict__ Ct,
                                               float* __restrict__ At) {
  __shared__ float colbuf[2][64];
  __shared__ __align__(16) float rowbuf[2][128];
  const int r = threadIdx.x & 63;
  const int cgrp = threadIdx.x >> 6;
  float creg[32];
  #pragma unroll
  for (int cc = 0; cc < 32; ++cc)
    creg[cc] = Ct[(cgrp * 32 + cc) * 64 + r];
  #pragma unroll
  for (int p = 0; p < 64; ++p) {
    const int pb = p & 1, pc = p >> 5, pi = p & 31;
    if (cgrp == pc) colbuf[pb][r] = creg[pi];
    if (r == p) {
      #pragma unroll
      for (int cc = 0; cc < 32; ++cc) rowbuf[pb][cgrp * 32 + cc] = creg[cc];
    }
    __syncthreads();
    const float f = colbuf[pb][r];
    const float inv = 1.0f / colbuf[pb][p];
    if (r == p) {
      #pragma unroll
      for (int cc = 0; cc < 32; ++cc) creg[cc] *= inv;
    } else {
      const float gg = f * inv;
      #pragma unroll
      for (int c4 = 0; c4 < 8; ++c4) {
        const float4 pv = *(const float4*)&rowbuf[pb][cgrp * 32 + c4 * 4];
        creg[c4 * 4 + 0] -= gg * pv.x;
        creg[c4 * 4 + 1] -= gg * pv.y;
        creg[c4 * 4 + 2] -= gg * pv.z;
        creg[c4 * 4 + 3] -= gg * pv.w;
      }
    }
  }
  if (cgrp >= 2) {
    #pragma unroll
    for (int cc = 0; cc < 32; ++cc) {
      int k = (cgrp - 2) * 32 + cc;
      At[k * 64 + r] = creg[cc];
    }
  }
}

// ---------------- Kernel C: out = A @ X, X = x viewed (64, SN) ------------------------
// Block = 4 waves sharing one 64-float4 (=256 col) j-window; wave w owns i-quarter
// [16w, 16w+16). Per thread: acc[16][4] (64 VGPRs). Per k-step per wave:
// 4 uniform ds_read_b128 (broadcast, conflict-free) + 1 coalesced dwordx4 x-load
// + 64 FMAs. Branchless clamped 1-deep prefetch.
__global__ __launch_bounds__(256) void k_apply(const float* __restrict__ x,
                                               const float* __restrict__ At,
                                               float* __restrict__ out) {
  __shared__ f32x4 Al[1024];  // Al[k*16 + i4] = A[4*i4 .. 4*i4+3][k]
  const f32x4* At4 = (const f32x4*)At;
  #pragma unroll
  for (int it = 0; it < 4; ++it)
    Al[threadIdx.x + it * 256] = At4[threadIdx.x + it * 256];
  __syncthreads();

  const int lane = threadIdx.x & 63;
  const int w = threadIdx.x >> 6;         // i-quarter owner
  const int c = blockIdx.x * 64 + lane;   // float4-column index
  const f32x4* x4 = (const f32x4*)x;
  f32x4* out4 = (f32x4*)out;

  float acc[16][4];
  #pragma unroll
  for (int il = 0; il < 16; ++il)
    #pragma unroll
    for (int j = 0; j < 4; ++j) acc[il][j] = 0.f;

  f32x4 xa = x4[c];
  #pragma unroll 4
  for (int k = 0; k < 64; ++k) {
    const int kn = (k < 63) ? (k + 1) : 63;      // clamped: branchless prefetch
    const f32x4 nx = x4[kn * (SN / 4) + c];
    #pragma unroll
    for (int q = 0; q < 4; ++q) {
      const f32x4 a = Al[(k << 4) + (w << 2) + q];  // uniform -> LDS broadcast
      #pragma unroll
      for (int r = 0; r < 4; ++r) {
        const float av = a[r];
        const int il = q * 4 + r;
        acc[il][0] += av * xa[0];
        acc[il][1] += av * xa[1];
        acc[il][2] += av * xa[2];
        acc[il][3] += av * xa[3];
      }
    }
    xa = nx;
  }

  #pragma unroll
  for (int il = 0; il < 16; ++il) {
    const int i = w * 16 + il;
    f32x4 v = {acc[il][0], acc[il][1], acc[il][2], acc[il][3]};
    out4[i * (SN / 4) + c] = v;
  }
}

extern "C" void kernel_launch(void* const* d_in, const int* in_sizes, int n_in,
                              void* d_out, int out_size, void* d_ws, size_t ws_size,
                              hipStream_t stream) {
  const float* x = (const float*)d_in[0];  // 524288 x 64
  const float* L = (const float*)d_in[1];  // 128 x 128
  const float* R = (const float*)d_in[2];  // 64 x 64
  float* out = (float*)d_out;
  float* Ct = (float*)d_ws;        // 128*64 f32 = 32 KB
  float* At = Ct + 128 * 64;       // 64*64 f32 = 16 KB
  k_buildC<<<32, 256, 0, stream>>>(L, R, Ct);
  k_solve<<<1, 256, 0, stream>>>(Ct, At);
  k_apply<<<2048, 256, 0, stream>>>(x, At, out);
}